// Round 7
// baseline (2955.744 us; speedup 1.0000x reference)
//
#include <hip/hip_runtime.h>

typedef _Float16 f16;
typedef _Float16 f16x8 __attribute__((ext_vector_type(8)));
typedef float f32x4 __attribute__((ext_vector_type(4)));

#define MFMA(a,b,c) __builtin_amdgcn_mfma_f32_16x16x32_f16(a,b,c,0,0,0)

constexpr int B_ = 2048, V_ = 128, EGO_ = 15, H_ = 256;
constexpr int MT = 16;           // batch rows per block (one 16-row m-tile)
constexpr int ENC_KT = 9;        // K = 288 = 256(h) + 32(x padded)
constexpr int DEC_KT = 8;        // K = 256
constexpr int HSTR = 296;        // f16 row stride (16B aligned)
constexpr int DSTR = 264;

__device__ __forceinline__ float sigf(float x){ return 1.f/(1.f+__expf(-x)); }
__device__ __forceinline__ float tanh_fast(float x){ return 1.f - 2.f/(1.f+__expf(2.f*x)); }

// JOURNAL (R4-R6): all cross-block flag/spin exchange variants failed the
// harness's post-replay revalidation (deterministically wrong replay output)
// even when first-call validation passed. This design has NO inter-block
// communication: one 1024-thread block owns 16 batch rows end-to-end; the
// full weight matrix is register-resident split across 16 waves; h-state
// exchange is LDS + __syncthreads only.

// ---- prepack: weights -> per-(w,gate) MFMA B-fragment order ----
// id = ((w*4+g)*KT + kt)*64 + lane
// n = g*256 + w*16 + (lane&15); k = kt*32 + (lane>>4)*8 + j
__global__ void prepack_enc(const float* __restrict__ Whh1, const float* __restrict__ Wih1,
                            f16* __restrict__ dst){
    int id = blockIdx.x*256 + threadIdx.x;
    if (id >= 16*4*ENC_KT*64) return;
    int L = id & 63; int c = id >> 6;
    int kt = c % ENC_KT; int m = c / ENC_KT;
    int g = m & 3, w = m >> 2;
    int n = g*256 + w*16 + (L&15);
    int kbase = kt*32 + (L>>4)*8;
    #pragma unroll
    for (int j=0;j<8;++j){
        int k = kbase + j;
        float x = (k < 256) ? Whh1[n*256 + k] : ((k < 271) ? Wih1[n*15 + (k-256)] : 0.f);
        dst[(size_t)id*8 + j] = (f16)x;
    }
}
__global__ void prepack_dec(const float* __restrict__ Whh2, f16* __restrict__ dst){
    int id = blockIdx.x*256 + threadIdx.x;
    if (id >= 16*4*DEC_KT*64) return;
    int L = id & 63; int c = id >> 6;
    int kt = c % DEC_KT; int m = c / DEC_KT;
    int g = m & 3, w = m >> 2;
    int n = g*256 + w*16 + (L&15);
    int kbase = kt*32 + (L>>4)*8;
    #pragma unroll
    for (int j=0;j<8;++j) dst[(size_t)id*8 + j] = (f16)Whh2[n*256 + kbase + j];
}
__global__ void bias_kernel(const float* bih1,const float* bhh1,const float* bih2,
                            const float* bhh2,float* be,float* bd){
    int i = blockIdx.x*256 + threadIdx.x;
    if (i < 1024){ be[i]=bih1[i]+bhh1[i]; bd[i]=bih2[i]+bhh2[i]; }
}
__global__ void convert_kernel(const float* __restrict__ src, f16* __restrict__ dst, int n){
    int i = blockIdx.x*256 + threadIdx.x;
    if (i < n) dst[i] = (f16)src[i];
}

// ---- encoder: 128 blocks x 1024 threads; 16 waves each own 16 h-units x 4 gates ----
__global__ __launch_bounds__(1024,4) void encoder_kernel(
    const float* __restrict__ state, const int* __restrict__ lengths,
    const f16* __restrict__ Wp, const float* __restrict__ bias,
    f16* __restrict__ henc)
{
    __shared__ __align__(16) f16 hcat[MT*HSTR];
    const int tid = threadIdx.x;
    const int w = tid>>6, lane = tid&63, lr = lane&15, quad = lane>>4;
    const int row0 = blockIdx.x*MT;

    for (int i=tid;i<MT*HSTR;i+=1024) hcat[i] = (f16)0.f;

    int len_r[4];
    #pragma unroll
    for (int r=0;r<4;++r) len_r[r] = lengths[row0 + quad*4 + r];

    float bias_v[4];
    #pragma unroll
    for (int g=0;g<4;++g) bias_v[g] = bias[g*256 + w*16 + lr];

    // wave w's weight slice: 4 gates x 9 k-frags = 144 VGPRs, loop-resident
    const f16x8* Wb = (const f16x8*)Wp + (size_t)w*4*ENC_KT*64;
    f16x8 wreg[4][ENC_KT];
    #pragma unroll
    for (int g=0;g<4;++g)
        #pragma unroll
        for (int kt=0;kt<ENC_KT;++kt)
            wreg[g][kt] = Wb[(g*ENC_KT + kt)*64 + lane];

    float c_reg[4], h_reg[4];
    #pragma unroll
    for (int i=0;i<4;++i){ c_reg[i]=0.f; h_reg[i]=0.f; }

    for (int t=0;t<V_;++t){
        if (tid < 240){
            int rr = tid/15, cc = tid - rr*15;
            hcat[rr*HSTR + 256 + cc] = (f16)state[(size_t)(row0+rr)*V_*EGO_ + t*EGO_ + cc];
        }
        __syncthreads();                                   // B1: h+x staged
        f32x4 acc[4];
        #pragma unroll
        for (int g=0;g<4;++g)
            acc[g] = (f32x4){bias_v[g],bias_v[g],bias_v[g],bias_v[g]};
        #pragma unroll
        for (int kt=0;kt<ENC_KT;++kt){
            f16x8 a = *(const f16x8*)&hcat[lr*HSTR + kt*32 + quad*8];
            #pragma unroll
            for (int g=0;g<4;++g) acc[g] = MFMA(a, wreg[g][kt], acc[g]);
        }
        __syncthreads();                                   // B2: MFMA reads done
        #pragma unroll
        for (int r=0;r<4;++r){
            float gi = acc[0][r], gf = acc[1][r], gg = acc[2][r], go = acc[3][r];
            float cn = sigf(gf)*c_reg[r] + sigf(gi)*tanh_fast(gg);
            float hn = sigf(go)*tanh_fast(cn);
            bool upd = (t < len_r[r]);
            c_reg[r] = upd ? cn : c_reg[r];
            h_reg[r] = upd ? hn : h_reg[r];
            hcat[(quad*4+r)*HSTR + w*16 + lr] = (f16)h_reg[r];
        }
        // next-iteration B1 orders these h-writes before the MFMA reads
    }
    #pragma unroll
    for (int r=0;r<4;++r)
        henc[(size_t)(row0+quad*4+r)*H_ + w*16 + lr] = (f16)h_reg[r];
}

// ---- generic GEMM: C = act(A[M,K] @ W[N,K]^T + bias) ----
template<bool RELU, bool F32OUT>
__global__ __launch_bounds__(256,2) void gemm_kernel(
    const f16* __restrict__ A, const f16* __restrict__ W,
    const float* __restrict__ bias, void* __restrict__ outp,
    int M, int N, int K)
{
    constexpr int ASTR = 40;
    __shared__ __align__(16) f16 As[64*ASTR];
    __shared__ __align__(16) f16 Ws[64*ASTR];
    const int tid = threadIdx.x;
    const int wave = tid>>6, lane = tid&63, lr = lane&15, quad = lane>>4;
    const int n0 = blockIdx.x*64, m0 = blockIdx.y*64;
    const int lrow = tid>>2, lk8 = (tid&3)*8;

    f32x4 acc[4];
    #pragma unroll
    for (int mt=0;mt<4;++mt) acc[mt] = (f32x4){0.f,0.f,0.f,0.f};

    for (int k0=0;k0<K;k0+=32){
        __syncthreads();
        *(f16x8*)&As[lrow*ASTR + lk8] = *(const f16x8*)&A[(size_t)(m0+lrow)*K + k0 + lk8];
        *(f16x8*)&Ws[lrow*ASTR + lk8] = *(const f16x8*)&W[(size_t)(n0+lrow)*K + k0 + lk8];
        __syncthreads();
        f16x8 b = *(const f16x8*)&Ws[(wave*16+lr)*ASTR + quad*8];
        #pragma unroll
        for (int mt=0;mt<4;++mt){
            f16x8 a = *(const f16x8*)&As[(mt*16+lr)*ASTR + quad*8];
            acc[mt] = MFMA(a, b, acc[mt]);
        }
    }
    float bv = bias[n0 + wave*16 + lr];
    #pragma unroll
    for (int mt=0;mt<4;++mt){
        #pragma unroll
        for (int r=0;r<4;++r){
            float v = acc[mt][r] + bv;
            if (RELU) v = fmaxf(v, 0.f);
            int m = m0 + mt*16 + quad*4 + r, n = n0 + wave*16 + lr;
            if (F32OUT) ((float*)outp)[(size_t)m*N + n] = v;
            else        ((f16*)outp)[(size_t)m*N + n] = (f16)v;
        }
    }
}

// ---- decoder: 128 blocks x 1024 threads, register weights, fused pi head ----
__global__ __launch_bounds__(1024,4) void decoder_kernel(
    const int* __restrict__ lengths, const f16* __restrict__ Wp,
    const float* __restrict__ xdec, const float* __restrict__ Wpi,
    const float* __restrict__ bpi, float* __restrict__ out)
{
    __shared__ __align__(16) f16 hbuf[MT*DSTR];
    __shared__ float part[16][16][2];
    const int tid = threadIdx.x;
    const int w = tid>>6, lane = tid&63, lr = lane&15, quad = lane>>4;
    const int row0 = blockIdx.x*MT;

    for (int i=tid;i<MT*DSTR;i+=1024) hbuf[i] = (f16)0.f;

    float xd[4][4];
    #pragma unroll
    for (int g=0;g<4;++g){
        int n = g*256 + w*16 + lr;
        #pragma unroll
        for (int r=0;r<4;++r)
            xd[g][r] = xdec[(size_t)(row0+quad*4+r)*1024 + n];
    }
    float wpi_reg[2];
    #pragma unroll
    for (int a=0;a<2;++a) wpi_reg[a] = Wpi[a*H_ + w*16 + lr];

    const f16x8* Wb = (const f16x8*)Wp + (size_t)w*4*DEC_KT*64;
    f16x8 wreg[4][DEC_KT];
    #pragma unroll
    for (int g=0;g<4;++g)
        #pragma unroll
        for (int kt=0;kt<DEC_KT;++kt)
            wreg[g][kt] = Wb[(g*DEC_KT + kt)*64 + lane];

    float c_reg[4];
    #pragma unroll
    for (int i=0;i<4;++i) c_reg[i]=0.f;

    const int orow = tid>>1, oa = tid&1;               // tid<32: output row/act
    const float bpi_o = bpi[oa];
    const int len_o = (tid<32) ? lengths[row0+orow] : 0;

    for (int t=0;t<V_;++t){
        __syncthreads();                                   // B1: h staged
        f32x4 acc[4];
        #pragma unroll
        for (int g=0;g<4;++g)
            acc[g] = (f32x4){xd[g][0],xd[g][1],xd[g][2],xd[g][3]};
        #pragma unroll
        for (int kt=0;kt<DEC_KT;++kt){
            f16x8 a = *(const f16x8*)&hbuf[lr*DSTR + kt*32 + quad*8];
            #pragma unroll
            for (int g=0;g<4;++g) acc[g] = MFMA(a, wreg[g][kt], acc[g]);
        }
        __syncthreads();                                   // B2: MFMA reads done
        float spi[4][2];
        #pragma unroll
        for (int r=0;r<4;++r){
            float gi = acc[0][r], gf = acc[1][r], gg = acc[2][r], go = acc[3][r];
            float cn = sigf(gf)*c_reg[r] + sigf(gi)*tanh_fast(gg);
            c_reg[r] = cn;
            float hn = sigf(go)*tanh_fast(cn);
            hbuf[(quad*4+r)*DSTR + w*16 + lr] = (f16)hn;
            spi[r][0] = cn*wpi_reg[0];
            spi[r][1] = cn*wpi_reg[1];
        }
        #pragma unroll
        for (int msk=1; msk<16; msk<<=1){
            #pragma unroll
            for (int r=0;r<4;++r){
                spi[r][0] += __shfl_xor(spi[r][0], msk, 64);
                spi[r][1] += __shfl_xor(spi[r][1], msk, 64);
            }
        }
        if (lr == 0){
            #pragma unroll
            for (int r=0;r<4;++r){
                part[w][quad*4+r][0] = spi[r][0];
                part[w][quad*4+r][1] = spi[r][1];
            }
        }
        __syncthreads();                                   // B3: partials visible
        if (tid < 32){
            float v = bpi_o;
            #pragma unroll
            for (int ww=0;ww<16;++ww) v += part[ww][orow][oa];
            v = tanh_fast(v);
            out[((size_t)(row0+orow)*V_ + t)*2 + oa] = (t < len_o) ? v : 0.f;
        }
        // next-iteration B1 orders the h-writes before the MFMA reads
    }
}

extern "C" void kernel_launch(void* const* d_in, const int* in_sizes, int n_in,
                              void* d_out, int out_size, void* d_ws, size_t ws_size,
                              hipStream_t stream) {
    const float* state = (const float*)d_in[0];
    const int*   lengths=(const int*)d_in[1];
    const float* Wih1 = (const float*)d_in[2];
    const float* Whh1 = (const float*)d_in[3];
    const float* bih1 = (const float*)d_in[4];
    const float* bhh1 = (const float*)d_in[5];
    const float* W1   = (const float*)d_in[6];  const float* b1 = (const float*)d_in[7];
    const float* W2   = (const float*)d_in[8];  const float* b2 = (const float*)d_in[9];
    const float* W3   = (const float*)d_in[10]; const float* b3 = (const float*)d_in[11];
    const float* W4   = (const float*)d_in[12]; const float* b4 = (const float*)d_in[13];
    const float* Wih2 = (const float*)d_in[14]; const float* Whh2=(const float*)d_in[15];
    const float* bih2 = (const float*)d_in[16]; const float* bhh2=(const float*)d_in[17];
    const float* Wpi  = (const float*)d_in[18]; const float* bpi =(const float*)d_in[19];
    float* out = (float*)d_out;

    char* p = (char*)d_ws;
    auto alloc = [&](size_t bytes){ char* r = p; p += (bytes + 255) & ~(size_t)255; return r; };
    f16* WencP   = (f16*)alloc((size_t)16*4*ENC_KT*64*8*2);
    f16* WdecP   = (f16*)alloc((size_t)16*4*DEC_KT*64*8*2);
    f16* W1f     = (f16*)alloc((size_t)1024*256*2);
    f16* W2f     = (f16*)alloc((size_t)1024*1024*2);
    f16* W3f     = (f16*)alloc((size_t)512*1024*2);
    f16* W4f     = (f16*)alloc((size_t)256*512*2);
    f16* Wih2f   = (f16*)alloc((size_t)1024*256*2);
    float* biasE = (float*)alloc(1024*4);
    float* biasD = (float*)alloc(1024*4);
    f16* henc    = (f16*)alloc((size_t)2048*256*2);
    f16* act1    = (f16*)alloc((size_t)2048*1024*2);
    f16* act2    = (f16*)alloc((size_t)2048*1024*2);
    f16* act3    = (f16*)alloc((size_t)2048*512*2);
    f16* x4      = (f16*)alloc((size_t)2048*256*2);
    float* xdec  = (float*)alloc((size_t)2048*1024*4);

    prepack_enc<<<(16*4*ENC_KT*64+255)/256,256,0,stream>>>(Whh1, Wih1, WencP);
    prepack_dec<<<(16*4*DEC_KT*64+255)/256,256,0,stream>>>(Whh2, WdecP);
    bias_kernel<<<4,256,0,stream>>>(bih1,bhh1,bih2,bhh2,biasE,biasD);
    convert_kernel<<<(1024*256+255)/256,256,0,stream>>>(W1, W1f, 1024*256);
    convert_kernel<<<(1024*1024+255)/256,256,0,stream>>>(W2, W2f, 1024*1024);
    convert_kernel<<<(512*1024+255)/256,256,0,stream>>>(W3, W3f, 512*1024);
    convert_kernel<<<(256*512+255)/256,256,0,stream>>>(W4, W4f, 256*512);
    convert_kernel<<<(1024*256+255)/256,256,0,stream>>>(Wih2, Wih2f, 1024*256);

    encoder_kernel<<<B_/MT,1024,0,stream>>>(state, lengths, WencP, biasE, henc);

    gemm_kernel<true ,false><<<dim3(16,32),256,0,stream>>>(henc, W1f, b1, act1, 2048,1024,256);
    gemm_kernel<true ,false><<<dim3(16,32),256,0,stream>>>(act1, W2f, b2, act2, 2048,1024,1024);
    gemm_kernel<true ,false><<<dim3( 8,32),256,0,stream>>>(act2, W3f, b3, act3, 2048, 512,1024);
    gemm_kernel<true ,false><<<dim3( 4,32),256,0,stream>>>(act3, W4f, b4, x4,   2048, 256, 512);
    gemm_kernel<false,true ><<<dim3(16,32),256,0,stream>>>(x4, Wih2f, biasD, xdec, 2048,1024,256);

    decoder_kernel<<<B_/MT,1024,0,stream>>>(lengths, WdecP, xdec, Wpi, bpi, out);
}

// Round 8
// 1360.067 us; speedup vs baseline: 2.1732x; 2.1732x over previous
//
#include <hip/hip_runtime.h>

typedef _Float16 f16;
typedef _Float16 f16x8 __attribute__((ext_vector_type(8)));
typedef float f32x4 __attribute__((ext_vector_type(4)));

#define MFMA(a,b,c) __builtin_amdgcn_mfma_f32_16x16x32_f16(a,b,c,0,0,0)

constexpr int B_ = 2048, V_ = 128, EGO_ = 15, H_ = 256;
constexpr int MT = 16;           // batch rows per group
constexpr int ENC_KT = 9;        // K = 288 = 256(h) + 32(x padded)
constexpr int DEC_KT = 8;        // K = 256
constexpr int ENC_KR = 5;        // kts in RF (enc): wreg[8][5] = 160 VGPRs
constexpr int DEC_KR = 4;        // kts in RF (dec): wreg[8][4] = 128 VGPRs
constexpr int HSTR = 296;        // f16 row stride (16B aligned)
constexpr int DSTR = 264;

// JOURNAL: R3 (pair-split + relaxed-bypass exchange) PASSED replay; 4-way
// quartet variants (R4-R6) failed replay; 1024-thread no-sync (R7) passed but
// capped waves at 128 VGPR -> weight remat -> 2x slower. R8 = R3 structure
// verbatim + RF/LDS weight split so the 288KB/block weight set is fully
// CU-resident (160 VGPR/wave in RF + 128KB in LDS), zero per-step streaming.

__device__ __forceinline__ float sigf(float x){ return 1.f/(1.f+__expf(-x)); }
__device__ __forceinline__ float tanh_fast(float x){ return 1.f - 2.f/(1.f+__expf(2.f*x)); }

// relaxed agent-scope ops: coherent bypass of L1/L2, no cache-wide maintenance.
// RULE: cross-block data written via st_* MUST be read via ld_* (stale-L1 bug, R5).
__device__ __forceinline__ void st_u32(uint32_t* p, uint32_t v){
    __hip_atomic_store(p, v, __ATOMIC_RELAXED, __HIP_MEMORY_SCOPE_AGENT);
}
__device__ __forceinline__ uint32_t ld_u32(const uint32_t* p){
    return __hip_atomic_load(p, __ATOMIC_RELAXED, __HIP_MEMORY_SCOPE_AGENT);
}
union cvt8 { f16x8 h; uint32_t u[4]; };

// ---- prepack: weights -> per-(hb,wave) MFMA B-fragment order (R3 layout) ----
// id = (((hb*4+w)*8+nt)*KT+kt)*64+L ; nt=(gate<<1)|s
// n = gate*256 + hb*128 + w*32 + s*16 + (L&15); k = kt*32 + (L>>4)*8 + j
__global__ void prepack_enc(const float* __restrict__ Whh1, const float* __restrict__ Wih1,
                            f16* __restrict__ dst){
    int id = blockIdx.x*256 + threadIdx.x;
    if (id >= 2*4*8*ENC_KT*64) return;
    int L = id & 63; int c = id >> 6;
    int kt = c % ENC_KT; c /= ENC_KT;
    int nt = c & 7; c >>= 3;
    int w = c & 3; int hb = c >> 2;
    int n = (nt>>1)*256 + hb*128 + w*32 + (nt&1)*16 + (L&15);
    int kbase = kt*32 + (L>>4)*8;
    #pragma unroll
    for (int j=0;j<8;++j){
        int k = kbase + j;
        float x = (k < 256) ? Whh1[n*256 + k] : ((k < 271) ? Wih1[n*15 + (k-256)] : 0.f);
        dst[(size_t)id*8 + j] = (f16)x;
    }
}
__global__ void prepack_dec(const float* __restrict__ Whh2, f16* __restrict__ dst){
    int id = blockIdx.x*256 + threadIdx.x;
    if (id >= 2*4*8*DEC_KT*64) return;
    int L = id & 63; int c = id >> 6;
    int kt = c % DEC_KT; c /= DEC_KT;
    int nt = c & 7; c >>= 3;
    int w = c & 3; int hb = c >> 2;
    int n = (nt>>1)*256 + hb*128 + w*32 + (nt&1)*16 + (L&15);
    int kbase = kt*32 + (L>>4)*8;
    #pragma unroll
    for (int j=0;j<8;++j) dst[(size_t)id*8 + j] = (f16)Whh2[n*256 + kbase + j];
}
__global__ void bias_kernel(const float* bih1,const float* bhh1,const float* bih2,
                            const float* bhh2,float* be,float* bd){
    int i = blockIdx.x*256 + threadIdx.x;
    if (i < 1024){ be[i]=bih1[i]+bhh1[i]; bd[i]=bih2[i]+bhh2[i]; }
}
__global__ void convert_kernel(const float* __restrict__ src, f16* __restrict__ dst, int n){
    int i = blockIdx.x*256 + threadIdx.x;
    if (i < n) dst[i] = (f16)src[i];
}

// ---- encoder: 256 blocks (pair i <-> i^128), weights CU-resident (RF+LDS) ----
__global__ __launch_bounds__(256,1) void encoder_kernel(
    const float* __restrict__ state, const int* __restrict__ lengths,
    const f16* __restrict__ Wp, const float* __restrict__ bias,
    f16* __restrict__ henc, f16* __restrict__ ebuf, int* __restrict__ flags)
{
    __shared__ __align__(16) f16 wlds[4*8*(ENC_KT-ENC_KR)*64*8];  // 128 KB
    __shared__ __align__(16) f16 hcat[MT*HSTR];
    const int tid = threadIdx.x;
    const int wave = tid>>6, lane = tid&63, lr = lane&15, quad = lane>>4;
    const int bid = blockIdx.x, hb = bid>>7, g = bid&127, pbid = bid^128;
    const int row0 = g*MT;
    const int xr = tid>>4, xc = tid&15;   // exchange: 16 rows x 16 col-groups

    for (int i=tid;i<MT*HSTR;i+=256) hcat[i] = (f16)0.f;

    int len_r[4];
    #pragma unroll
    for (int r=0;r<4;++r) len_r[r] = lengths[row0 + quad*4 + r];

    float bias_v[8];
    #pragma unroll
    for (int nt=0;nt<8;++nt)
        bias_v[nt] = bias[(nt>>1)*256 + hb*128 + wave*32 + (nt&1)*16 + lr];

    const f16x8* Wb = (const f16x8*)Wp + (size_t)((hb*4+wave)*8*ENC_KT)*64;
    // RF half: kts [0,5) -> 160 VGPRs (kept under compiler's remat threshold)
    f16x8 wreg[8][ENC_KR];
    #pragma unroll
    for (int nt=0;nt<8;++nt)
        #pragma unroll
        for (int kt=0;kt<ENC_KR;++kt)
            wreg[nt][kt] = Wb[(nt*ENC_KT + kt)*64 + lane];
    // LDS half: kts [5,9) -> wave-private 32 KB slice
    f16x8* wl = (f16x8*)wlds + (size_t)wave*(8*(ENC_KT-ENC_KR)*64);
    #pragma unroll
    for (int nt=0;nt<8;++nt)
        #pragma unroll
        for (int kt=0;kt<ENC_KT-ENC_KR;++kt)
            wl[(nt*(ENC_KT-ENC_KR) + kt)*64 + lane] = Wb[(nt*ENC_KT + ENC_KR + kt)*64 + lane];

    float c_reg[8], h_reg[8];
    #pragma unroll
    for (int i=0;i<8;++i){ c_reg[i]=0.f; h_reg[i]=0.f; }

    for (int t=0;t<V_;++t){
        if (tid < 240){
            int rr = tid/15, cc = tid - rr*15;
            hcat[rr*HSTR + 256 + cc] = (f16)state[(size_t)(row0+rr)*V_*EGO_ + t*EGO_ + cc];
        }
        __syncthreads();                                   // B1
        f32x4 acc[8];
        #pragma unroll
        for (int nt=0;nt<8;++nt) acc[nt] = (f32x4){bias_v[nt],bias_v[nt],bias_v[nt],bias_v[nt]};
        #pragma unroll
        for (int kt=0;kt<ENC_KR;++kt){
            f16x8 a = *(const f16x8*)&hcat[lr*HSTR + kt*32 + quad*8];
            #pragma unroll
            for (int nt=0;nt<8;++nt) acc[nt] = MFMA(a, wreg[nt][kt], acc[nt]);
        }
        #pragma unroll
        for (int kt=0;kt<ENC_KT-ENC_KR;++kt){
            f16x8 a = *(const f16x8*)&hcat[lr*HSTR + (ENC_KR+kt)*32 + quad*8];
            #pragma unroll
            for (int nt=0;nt<8;++nt)
                acc[nt] = MFMA(a, wl[(nt*(ENC_KT-ENC_KR) + kt)*64 + lane], acc[nt]);
        }
        __syncthreads();                                   // B2
        #pragma unroll
        for (int s=0;s<2;++s){
            #pragma unroll
            for (int r=0;r<4;++r){
                int idx = s*4 + r;
                float gi = acc[s][r],   gf = acc[2+s][r];
                float gg = acc[4+s][r], go = acc[6+s][r];
                float cn = sigf(gf)*c_reg[idx] + sigf(gi)*tanh_fast(gg);
                float hn = sigf(go)*tanh_fast(cn);
                bool upd = (t < len_r[r]);
                c_reg[idx] = upd ? cn : c_reg[idx];
                h_reg[idx] = upd ? hn : h_reg[idx];
                hcat[(quad*4+r)*HSTR + hb*128 + wave*32 + s*16 + lr] = (f16)h_reg[idx];
            }
        }
        __syncthreads();                                   // B3a: own h-half in LDS
        {   // push own half to LLC: 4 bypass u32 stores/thread (R3 verbatim)
            cvt8 cv; cv.h = *(const f16x8*)&hcat[xr*HSTR + hb*128 + xc*8];
            uint32_t* dst = (uint32_t*)(ebuf + ((size_t)(t&1)*256 + bid)*2048) + xr*64 + xc*4;
            st_u32(dst+0,cv.u[0]); st_u32(dst+1,cv.u[1]);
            st_u32(dst+2,cv.u[2]); st_u32(dst+3,cv.u[3]);
        }
        __syncthreads();  // B3b: per-wave s_waitcnt vmcnt(0) -> stores at coherence pt
        if (tid == 0){
            st_u32((uint32_t*)&flags[bid], (uint32_t)(t+1));
            while (ld_u32((const uint32_t*)&flags[pbid]) < (uint32_t)(t+1))
                __builtin_amdgcn_s_sleep(2);
        }
        __syncthreads();                                   // B4
        {   // pull partner half (bypass loads -> fresh) into our LDS
            const uint32_t* src = (const uint32_t*)(ebuf + ((size_t)(t&1)*256 + pbid)*2048) + xr*64 + xc*4;
            cvt8 cv;
            cv.u[0]=ld_u32(src+0); cv.u[1]=ld_u32(src+1);
            cv.u[2]=ld_u32(src+2); cv.u[3]=ld_u32(src+3);
            *(f16x8*)&hcat[xr*HSTR + (1-hb)*128 + xc*8] = cv.h;
        }
        // next-iteration B1 orders these LDS writes before the MFMA reads
    }
    #pragma unroll
    for (int s=0;s<2;++s)
        #pragma unroll
        for (int r=0;r<4;++r)
            henc[(size_t)(row0+quad*4+r)*H_ + hb*128 + wave*32 + s*16 + lr] = (f16)h_reg[s*4+r];
}

// ---- generic GEMM: C = act(A[M,K] @ W[N,K]^T + bias) ----
template<bool RELU, bool F32OUT>
__global__ __launch_bounds__(256,2) void gemm_kernel(
    const f16* __restrict__ A, const f16* __restrict__ W,
    const float* __restrict__ bias, void* __restrict__ outp,
    int M, int N, int K)
{
    constexpr int ASTR = 40;
    __shared__ __align__(16) f16 As[64*ASTR];
    __shared__ __align__(16) f16 Ws[64*ASTR];
    const int tid = threadIdx.x;
    const int wave = tid>>6, lane = tid&63, lr = lane&15, quad = lane>>4;
    const int n0 = blockIdx.x*64, m0 = blockIdx.y*64;
    const int lrow = tid>>2, lk8 = (tid&3)*8;

    f32x4 acc[4];
    #pragma unroll
    for (int mt=0;mt<4;++mt) acc[mt] = (f32x4){0.f,0.f,0.f,0.f};

    for (int k0=0;k0<K;k0+=32){
        __syncthreads();
        *(f16x8*)&As[lrow*ASTR + lk8] = *(const f16x8*)&A[(size_t)(m0+lrow)*K + k0 + lk8];
        *(f16x8*)&Ws[lrow*ASTR + lk8] = *(const f16x8*)&W[(size_t)(n0+lrow)*K + k0 + lk8];
        __syncthreads();
        f16x8 b = *(const f16x8*)&Ws[(wave*16+lr)*ASTR + quad*8];
        #pragma unroll
        for (int mt=0;mt<4;++mt){
            f16x8 a = *(const f16x8*)&As[(mt*16+lr)*ASTR + quad*8];
            acc[mt] = MFMA(a, b, acc[mt]);
        }
    }
    float bv = bias[n0 + wave*16 + lr];
    #pragma unroll
    for (int mt=0;mt<4;++mt){
        #pragma unroll
        for (int r=0;r<4;++r){
            float v = acc[mt][r] + bv;
            if (RELU) v = fmaxf(v, 0.f);
            int m = m0 + mt*16 + quad*4 + r, n = n0 + wave*16 + lr;
            if (F32OUT) ((float*)outp)[(size_t)m*N + n] = v;
            else        ((f16*)outp)[(size_t)m*N + n] = (f16)v;
        }
    }
}

// ---- decoder: pair-split, CU-resident weights (RF+LDS), fused pi head ------
__global__ __launch_bounds__(256,1) void decoder_kernel(
    const int* __restrict__ lengths, const f16* __restrict__ Wp,
    const float* __restrict__ xdec, const float* __restrict__ Wpi,
    const float* __restrict__ bpi, float* __restrict__ out,
    f16* __restrict__ ebuf, int* __restrict__ flags, float* __restrict__ pbuf)
{
    __shared__ __align__(16) f16 wlds[4*8*(DEC_KT-DEC_KR)*64*8];  // 128 KB
    __shared__ __align__(16) f16 hbuf[MT*DSTR];
    __shared__ float part[4][16][2];
    const int tid = threadIdx.x;
    const int wave = tid>>6, lane = tid&63, lr = lane&15, quad = lane>>4;
    const int bid = blockIdx.x, hb = bid>>7, g = bid&127, pbid = bid^128;
    const int row0 = g*MT;
    const int xr = tid>>4, xc = tid&15;

    for (int i=tid;i<MT*DSTR;i+=256) hbuf[i] = (f16)0.f;

    float xd[8][4];
    #pragma unroll
    for (int nt=0;nt<8;++nt){
        int n = (nt>>1)*256 + hb*128 + wave*32 + (nt&1)*16 + lr;
        #pragma unroll
        for (int r=0;r<4;++r) xd[nt][r] = xdec[(size_t)(row0+quad*4+r)*1024 + n];
    }
    float wpi_reg[2][2];
    #pragma unroll
    for (int a=0;a<2;++a)
        #pragma unroll
        for (int s=0;s<2;++s)
            wpi_reg[a][s] = Wpi[a*H_ + hb*128 + wave*32 + s*16 + lr];

    const f16x8* Wb = (const f16x8*)Wp + (size_t)((hb*4+wave)*8*DEC_KT)*64;
    f16x8 wreg[8][DEC_KR];
    #pragma unroll
    for (int nt=0;nt<8;++nt)
        #pragma unroll
        for (int kt=0;kt<DEC_KR;++kt)
            wreg[nt][kt] = Wb[(nt*DEC_KT + kt)*64 + lane];
    f16x8* wl = (f16x8*)wlds + (size_t)wave*(8*(DEC_KT-DEC_KR)*64);
    #pragma unroll
    for (int nt=0;nt<8;++nt)
        #pragma unroll
        for (int kt=0;kt<DEC_KT-DEC_KR;++kt)
            wl[(nt*(DEC_KT-DEC_KR) + kt)*64 + lane] = Wb[(nt*DEC_KT + DEC_KR + kt)*64 + lane];

    float c_reg[8];
    #pragma unroll
    for (int i=0;i<8;++i) c_reg[i]=0.f;

    const int m_o = (tid>>1)&15, a_o = tid&1;
    const float bpi_o = bpi[a_o];
    const int len_o = (tid<32) ? lengths[row0+m_o] : 0;
    const size_t outbase = (size_t)(row0+m_o)*V_*2 + a_o;

    for (int t=0;t<V_;++t){
        __syncthreads();                                   // B1
        f32x4 acc[8];
        #pragma unroll
        for (int nt=0;nt<8;++nt) acc[nt] = (f32x4){xd[nt][0],xd[nt][1],xd[nt][2],xd[nt][3]};
        #pragma unroll
        for (int kt=0;kt<DEC_KR;++kt){
            f16x8 a = *(const f16x8*)&hbuf[lr*DSTR + kt*32 + quad*8];
            #pragma unroll
            for (int nt=0;nt<8;++nt) acc[nt] = MFMA(a, wreg[nt][kt], acc[nt]);
        }
        #pragma unroll
        for (int kt=0;kt<DEC_KT-DEC_KR;++kt){
            f16x8 a = *(const f16x8*)&hbuf[lr*DSTR + (DEC_KR+kt)*32 + quad*8];
            #pragma unroll
            for (int nt=0;nt<8;++nt)
                acc[nt] = MFMA(a, wl[(nt*(DEC_KT-DEC_KR) + kt)*64 + lane], acc[nt]);
        }
        __syncthreads();                                   // B2
        float spi[4][2];
        #pragma unroll
        for (int r=0;r<4;++r){ spi[r][0]=0.f; spi[r][1]=0.f; }
        #pragma unroll
        for (int s=0;s<2;++s){
            #pragma unroll
            for (int r=0;r<4;++r){
                int idx = s*4 + r;
                float gi = acc[s][r],   gf = acc[2+s][r];
                float gg = acc[4+s][r], go = acc[6+s][r];
                float cn = sigf(gf)*c_reg[idx] + sigf(gi)*tanh_fast(gg);
                c_reg[idx] = cn;
                float hn = sigf(go)*tanh_fast(cn);
                hbuf[(quad*4+r)*DSTR + hb*128 + wave*32 + s*16 + lr] = (f16)hn;
                spi[r][0] += cn*wpi_reg[0][s];
                spi[r][1] += cn*wpi_reg[1][s];
            }
        }
        #pragma unroll
        for (int msk=1; msk<16; msk<<=1){
            #pragma unroll
            for (int r=0;r<4;++r){
                spi[r][0] += __shfl_xor(spi[r][0], msk, 64);
                spi[r][1] += __shfl_xor(spi[r][1], msk, 64);
            }
        }
        if (lr == 0){
            #pragma unroll
            for (int r=0;r<4;++r){
                part[wave][quad*4+r][0] = spi[r][0];
                part[wave][quad*4+r][1] = spi[r][1];
            }
        }
        __syncthreads();                                   // B3a: hbuf + part visible
        {   // push own h-half
            cvt8 cv; cv.h = *(const f16x8*)&hbuf[xr*DSTR + hb*128 + xc*8];
            uint32_t* dst = (uint32_t*)(ebuf + ((size_t)(t&1)*256 + bid)*2048) + xr*64 + xc*4;
            st_u32(dst+0,cv.u[0]); st_u32(dst+1,cv.u[1]);
            st_u32(dst+2,cv.u[2]); st_u32(dst+3,cv.u[3]);
        }
        if (hb == 1 && tid < 32){   // push pre-summed pi partials (32 floats)
            float v = part[0][m_o][a_o]+part[1][m_o][a_o]+part[2][m_o][a_o]+part[3][m_o][a_o];
            st_u32((uint32_t*)pbuf + ((size_t)(t&1)*128 + g)*32 + tid, __float_as_uint(v));
        }
        __syncthreads();  // B3b: vmcnt(0) drain before barrier
        if (tid == 0){
            st_u32((uint32_t*)&flags[bid], (uint32_t)(t+1));
            while (ld_u32((const uint32_t*)&flags[pbid]) < (uint32_t)(t+1))
                __builtin_amdgcn_s_sleep(2);
        }
        __syncthreads();                                   // B4
        {
            const uint32_t* src = (const uint32_t*)(ebuf + ((size_t)(t&1)*256 + pbid)*2048) + xr*64 + xc*4;
            cvt8 cv;
            cv.u[0]=ld_u32(src+0); cv.u[1]=ld_u32(src+1);
            cv.u[2]=ld_u32(src+2); cv.u[3]=ld_u32(src+3);
            *(f16x8*)&hbuf[xr*DSTR + (1-hb)*128 + xc*8] = cv.h;
        }
        if (hb == 0 && tid < 32){
            uint32_t pu = ld_u32((const uint32_t*)pbuf + ((size_t)(t&1)*128 + g)*32 + tid);
            float v = part[0][m_o][a_o] + part[1][m_o][a_o]
                    + part[2][m_o][a_o] + part[3][m_o][a_o]
                    + __uint_as_float(pu) + bpi_o;
            v = tanh_fast(v);
            out[outbase + (size_t)t*2] = (t < len_o) ? v : 0.f;
        }
    }
}

extern "C" void kernel_launch(void* const* d_in, const int* in_sizes, int n_in,
                              void* d_out, int out_size, void* d_ws, size_t ws_size,
                              hipStream_t stream) {
    const float* state = (const float*)d_in[0];
    const int*   lengths=(const int*)d_in[1];
    const float* Wih1 = (const float*)d_in[2];
    const float* Whh1 = (const float*)d_in[3];
    const float* bih1 = (const float*)d_in[4];
    const float* bhh1 = (const float*)d_in[5];
    const float* W1   = (const float*)d_in[6];  const float* b1 = (const float*)d_in[7];
    const float* W2   = (const float*)d_in[8];  const float* b2 = (const float*)d_in[9];
    const float* W3   = (const float*)d_in[10]; const float* b3 = (const float*)d_in[11];
    const float* W4   = (const float*)d_in[12]; const float* b4 = (const float*)d_in[13];
    const float* Wih2 = (const float*)d_in[14]; const float* Whh2=(const float*)d_in[15];
    const float* bih2 = (const float*)d_in[16]; const float* bhh2=(const float*)d_in[17];
    const float* Wpi  = (const float*)d_in[18]; const float* bpi =(const float*)d_in[19];
    float* out = (float*)d_out;

    char* p = (char*)d_ws;
    auto alloc = [&](size_t bytes){ char* r = p; p += (bytes + 255) & ~(size_t)255; return r; };
    f16* WencP   = (f16*)alloc((size_t)2*4*8*ENC_KT*64*8*2);
    f16* WdecP   = (f16*)alloc((size_t)2*4*8*DEC_KT*64*8*2);
    f16* W1f     = (f16*)alloc((size_t)1024*256*2);
    f16* W2f     = (f16*)alloc((size_t)1024*1024*2);
    f16* W3f     = (f16*)alloc((size_t)512*1024*2);
    f16* W4f     = (f16*)alloc((size_t)256*512*2);
    f16* Wih2f   = (f16*)alloc((size_t)1024*256*2);
    float* biasE = (float*)alloc(1024*4);
    float* biasD = (float*)alloc(1024*4);
    f16* henc    = (f16*)alloc((size_t)2048*256*2);
    f16* act1    = (f16*)alloc((size_t)2048*1024*2);
    f16* act2    = (f16*)alloc((size_t)2048*1024*2);
    f16* act3    = (f16*)alloc((size_t)2048*512*2);
    f16* x4      = (f16*)alloc((size_t)2048*256*2);
    float* xdec  = (float*)alloc((size_t)2048*1024*4);
    f16* ebuf    = (f16*)alloc((size_t)2*256*2048*2);
    float* pbuf  = (float*)alloc((size_t)2*128*32*4);
    int* flags   = (int*)alloc((size_t)512*4);   // [0:256)=enc, [256:512)=dec

    hipMemsetAsync(flags, 0, 512*4, stream);

    prepack_enc<<<(2*4*8*ENC_KT*64+255)/256,256,0,stream>>>(Whh1, Wih1, WencP);
    prepack_dec<<<(2*4*8*DEC_KT*64+255)/256,256,0,stream>>>(Whh2, WdecP);
    bias_kernel<<<4,256,0,stream>>>(bih1,bhh1,bih2,bhh2,biasE,biasD);
    convert_kernel<<<(1024*256+255)/256,256,0,stream>>>(W1, W1f, 1024*256);
    convert_kernel<<<(1024*1024+255)/256,256,0,stream>>>(W2, W2f, 1024*1024);
    convert_kernel<<<(512*1024+255)/256,256,0,stream>>>(W3, W3f, 512*1024);
    convert_kernel<<<(256*512+255)/256,256,0,stream>>>(W4, W4f, 256*512);
    convert_kernel<<<(1024*256+255)/256,256,0,stream>>>(Wih2, Wih2f, 1024*256);

    encoder_kernel<<<256,256,0,stream>>>(state, lengths, WencP, biasE, henc, ebuf, flags);

    gemm_kernel<true ,false><<<dim3(16,32),256,0,stream>>>(henc, W1f, b1, act1, 2048,1024,256);
    gemm_kernel<true ,false><<<dim3(16,32),256,0,stream>>>(act1, W2f, b2, act2, 2048,1024,1024);
    gemm_kernel<true ,false><<<dim3( 8,32),256,0,stream>>>(act2, W3f, b3, act3, 2048, 512,1024);
    gemm_kernel<true ,false><<<dim3( 4,32),256,0,stream>>>(act3, W4f, b4, x4,   2048, 256, 512);
    gemm_kernel<false,true ><<<dim3(16,32),256,0,stream>>>(x4, Wih2f, biasD, xdec, 2048,1024,256);

    decoder_kernel<<<256,256,0,stream>>>(lengths, WdecP, xdec, Wpi, bpi, out,
                                         ebuf, flags+256, pbuf);
}